// Round 9
// baseline (426.908 us; speedup 1.0000x reference)
//
#include <hip/hip_runtime.h>
#include <math.h>

// Shift_11261404250938: per-image shift(trunc(±10%)) + zero-fill, standardize,
// min-max normalize. Standardization cancels in the min-max step, so
// out = (shifted - min) / (max - min).
//
// R10 -> R11: R10 decomposed the passes: passA (gather, 3 VMEM/quad) 98us at
// 3.1 TB/s vs passB (linear, 2 VMEM/quad) ~42us at ~7.3 TB/s (roofline).
// Budget currency = VMEM instructions (~1.2-1.9 cy/instr/CU) x phase overlap.
// R0's fused algorithm is VMEM-minimal (4/quad) but 1 block/image phase-locks
// every CU (pure-read phase, barrier, pure-write phase -> 2.6 TB/s). R11 keeps
// the 4-VMEM/quad algorithm but runs it as B*8 small blocks with a PER-IMAGE
// 8-block barrier (ws atomics): ~2048 resident blocks hit the barrier at
// staggered times -> every CU carries a mix of phase-A readers and phase-B
// writers (the copy-shaped mix R10 proved fast), without R7's parallelism
// halving (all blocks do both phases). Mechanisms individually proven:
// encoded atomicMin/Max (R10), spin + agent acquire/release (R7), row-wise
// masked minmax (R5/R6), dual-load rotate gather (R2/R8).

constexpr int kC = 3, kH = 224, kW = 224;
constexpr int kCHW  = kC * kH * kW;  // 150528
constexpr int kROWS = kC * kH;       // 672
constexpr int kQPR  = kW / 4;        // 56 quads per row
constexpr int TB    = 256;           // 4 waves
constexpr int PARTS = 8;             // blocks per image
constexpr int WVB   = TB / 64;       // 4 waves per block
constexpr int RPW   = kROWS / (PARTS * WVB); // 21 contiguous rows per wave
constexpr int NB    = 7;             // load batch depth (21 = 3*7)

typedef float f32x4 __attribute__((ext_vector_type(4)));

// Order-preserving float -> uint encoding (monotone; R10-proven).
__device__ __forceinline__ unsigned enc_f(float f) {
    const unsigned u = __float_as_uint(f);
    return u ^ (((int)u >> 31) ? 0xFFFFFFFFu : 0x80000000u);
}
__device__ __forceinline__ float dec_f(unsigned e) {
    return __uint_as_float(e ^ ((e & 0x80000000u) ? 0x80000000u : 0xFFFFFFFFu));
}

__device__ __forceinline__ void shifts_for(const float* __restrict__ sfy,
                                           const float* __restrict__ sfx,
                                           int img, int& sy, int& sx)
{
    // Replicate reference fp32 order: ((f*2-1)*0.1f)*size, trunc toward zero.
    float ty = sfy[img] * 2.0f - 1.0f; ty *= 0.1f; ty *= (float)kH;
    sy = (int)truncf(ty);
    float tx = sfx[img] * 2.0f - 1.0f; tx *= 0.1f; tx *= (float)kW;
    sx = (int)truncf(tx);
}

// ---- Phase A: row-wise masked linear min/max (R5/R6-proven), batch-7 ----
__device__ __forceinline__ void phaseA_rows(const float* __restrict__ xb,
                                            int r0, int rlo, int rhi,
                                            int clo, int chi, int lane,
                                            float& vmin, float& vmax)
{
    if (lane >= kQPR) return;            // idle lanes keep seed values
    const int i0 = lane * 4;
    float cm[4];                         // loop-invariant column validity
    #pragma unroll
    for (int k = 0; k < 4; ++k)
        cm[k] = ((i0 + k) >= clo && (i0 + k) < chi) ? 1.0f : 0.0f;

    for (int t0 = 0; t0 < RPW; t0 += NB) {
        f32x4 v[NB];
        #pragma unroll
        for (int u = 0; u < NB; ++u)     // back-to-back loads, imm offsets
            v[u] = *(const f32x4*)(xb + (r0 + t0 + u) * kW + i0);
        #pragma unroll
        for (int u = 0; u < NB; ++u) {
            const int j = (r0 + t0 + u) % kH;          // wave-uniform scalar
            const float srm = (j >= rlo && j < rhi) ? 1.0f : 0.0f;
            #pragma unroll
            for (int k = 0; k < 4; ++k) {
                const float val = v[u][k] * cm[k] * srm;  // invalid -> 0 (legal)
                vmin = fminf(vmin, val);
                vmax = fmaxf(vmax, val);
            }
        }
    }
}

// ---- Phase B: dual-load rotate gather + normalize (R2/R8-proven), batch-7 ----
// R = sx & 3; bases multiple of 4 -> clamped lanes' wrong elements always
// masked. Invalid dest rows: clamped src row + scale=0 -> out = (0-mn)*inv.
template <int R>
__device__ __forceinline__ void phaseB_rows(const float* __restrict__ xb,
                                            float* __restrict__ ob,
                                            int r0, int sy, int sx,
                                            float inv, float zoff, int lane)
{
    if (lane >= kQPR) return;
    const int i0   = lane * 4;
    const int base = i0 + sx - R;                  // multiple of 4
    int qa = base;     qa = qa < 0 ? 0 : qa; qa = qa > kW - 4 ? kW - 4 : qa;
    int qb = base + 4; qb = qb < 0 ? 0 : qb; qb = qb > kW - 4 ? kW - 4 : qb;

    float cm[4];
    #pragma unroll
    for (int k = 0; k < 4; ++k)
        cm[k] = ((unsigned)(i0 + k + sx) < (unsigned)kW) ? 1.0f : 0.0f;

    for (int t0 = 0; t0 < RPW; t0 += NB) {
        f32x4 av[NB], bv[NB];
        #pragma unroll
        for (int u = 0; u < NB; ++u) {
            const int rr = r0 + t0 + u;            // output row in [0, C*H)
            const int j  = rr % kH;                // wave-uniform scalar
            const int jj = j + sy;
            const int jc = ((unsigned)jj < (unsigned)kH) ? jj : j;  // clamp
            const float* __restrict__ src = xb + (rr - j + jc) * kW;
            av[u] = *(const f32x4*)(src + qa);
            bv[u] = *(const f32x4*)(src + qb);     // L1-hit neighbor line
        }
        #pragma unroll
        for (int u = 0; u < NB; ++u) {
            const int rr = r0 + t0 + u;
            const int j  = rr % kH;
            const int jj = j + sy;
            const float scale = ((unsigned)jj < (unsigned)kH) ? inv : 0.0f;
            f32x4 o;
            #pragma unroll
            for (int k = 0; k < 4; ++k) {
                const float sel = (k + R < 4) ? av[u][k + R] : bv[u][k + R - 4];
                o[k] = fmaf(sel * cm[k], scale, zoff);  // invalid -> (0-mn)*inv
            }
            *(f32x4*)(ob + rr * kW + i0) = o;      // 16B aligned
        }
    }
}

__global__ __launch_bounds__(TB) void shift_norm_pi(
    const float* __restrict__ x, const float* __restrict__ sfy,
    const float* __restrict__ sfx, float* __restrict__ out,
    unsigned* __restrict__ umin, unsigned* __restrict__ umax,
    unsigned* __restrict__ cnt)
{
    const int gb   = blockIdx.x;
    const int img  = gb >> 3;                      // PARTS = 8
    const int part = gb & (PARTS - 1);
    const float* __restrict__ xb = x + (size_t)img * kCHW;
    float* __restrict__ ob = out + (size_t)img * kCHW;

    int sy, sx; shifts_for(sfy, sfx, img, sy, sx);

    // Valid input sub-rectangle (rows/cols of x that survive the shift).
    const int rlo = sy > 0 ? sy : 0;
    const int rhi = kH + (sy < 0 ? sy : 0);
    const int clo = sx > 0 ? sx : 0;
    const int chi = kW + (sx < 0 ? sx : 0);

    const int tid  = threadIdx.x;
    const int lane = tid & 63;
    const int wv   = __builtin_amdgcn_readfirstlane(tid >> 6); // wave-uniform
    const int r0   = part * (WVB * RPW) + wv * RPW; // this wave's 21 rows

    // Any nonzero shift introduces zero-fill -> 0 in value set covers every
    // multiplier-masked element's 0 contribution (R6-proven).
    const bool hasfill = (sy != 0) | (sx != 0);
    float vmin = hasfill ? 0.0f : INFINITY;
    float vmax = hasfill ? 0.0f : -INFINITY;

    phaseA_rows(xb, r0, rlo, rhi, clo, chi, lane, vmin, vmax);

    // Wave (64-lane) shuffle reduction, then cross-wave via LDS.
    #pragma unroll
    for (int off = 32; off > 0; off >>= 1) {
        vmin = fminf(vmin, __shfl_down(vmin, off));
        vmax = fmaxf(vmax, __shfl_down(vmax, off));
    }
    __shared__ float smin[WVB], smax[WVB];
    __shared__ float s_mn, s_inv;
    if (lane == 0) { smin[tid >> 6] = vmin; smax[tid >> 6] = vmax; }
    __syncthreads();
    if (tid == 0) {
        float mn = smin[0], mx = smax[0];
        #pragma unroll
        for (int w = 1; w < WVB; ++w) {
            mn = fminf(mn, smin[w]);
            mx = fmaxf(mx, smax[w]);
        }
        // Publish partial (device-scope atomics), then release via counter.
        atomicMin(&umin[img], enc_f(mn));
        atomicMax(&umax[img], enc_f(mx));
        __hip_atomic_fetch_add(&cnt[img], 1u, __ATOMIC_ACQ_REL,
                               __HIP_MEMORY_SCOPE_AGENT);
        // Per-image barrier: brothers are adjacent blockIdx and the grid is
        // massively co-resident (~2048 blocks; max dispatch skew ~7 blocks),
        // so spin is deadlock-free (R7 proved the mechanism executes).
        while (__hip_atomic_load(&cnt[img], __ATOMIC_ACQUIRE,
                                 __HIP_MEMORY_SCOPE_AGENT) < (unsigned)PARTS)
            __builtin_amdgcn_s_sleep(4);
        const float gmn = dec_f(__hip_atomic_load(&umin[img], __ATOMIC_RELAXED,
                                                  __HIP_MEMORY_SCOPE_AGENT));
        const float gmx = dec_f(__hip_atomic_load(&umax[img], __ATOMIC_RELAXED,
                                                  __HIP_MEMORY_SCOPE_AGENT));
        s_mn  = gmn;
        s_inv = 1.0f / (gmx - gmn);
    }
    __syncthreads();
    const float mn   = s_mn;
    const float inv  = s_inv;
    const float zoff = (0.0f - mn) * inv;

    switch (sx & 3) {
        case 0: phaseB_rows<0>(xb, ob, r0, sy, sx, inv, zoff, lane); break;
        case 1: phaseB_rows<1>(xb, ob, r0, sy, sx, inv, zoff, lane); break;
        case 2: phaseB_rows<2>(xb, ob, r0, sy, sx, inv, zoff, lane); break;
        default: phaseB_rows<3>(xb, ob, r0, sy, sx, inv, zoff, lane); break;
    }
}

extern "C" void kernel_launch(void* const* d_in, const int* in_sizes, int n_in,
                              void* d_out, int out_size, void* d_ws, size_t ws_size,
                              hipStream_t stream) {
    const float* x  = (const float*)d_in[0];
    const float* fy = (const float*)d_in[1];
    const float* fx = (const float*)d_in[2];
    float* out = (float*)d_out;
    const int B = in_sizes[1];          // shift_fy has one element per image

    unsigned* umin = (unsigned*)d_ws;   // [B], seed 0xFFFFFFFF (enc +huge)
    unsigned* umax = umin + B;          // [B], seed 0x00000000 (enc -huge)
    unsigned* cnt  = umax + B;          // [B], seed 0
    hipMemsetAsync(umin, 0xFF, (size_t)B * sizeof(unsigned), stream);
    hipMemsetAsync(umax, 0x00, (size_t)B * 2 * sizeof(unsigned), stream);

    shift_norm_pi<<<B * PARTS, TB, 0, stream>>>(x, fy, fx, out, umin, umax, cnt);
}

// Round 11
// 295.512 us; speedup vs baseline: 1.4446x; 1.4446x over previous
//
#include <hip/hip_runtime.h>
#include <math.h>

// Shift_11261404250938: per-image shift(trunc(±10%)) + zero-fill, standardize,
// min-max normalize. Standardization cancels in the min-max step, so
// out = (shifted - min) / (max - min).
//
// R12 -> R13: R12's misaligned-single-load idea was right (4 -> 3 mem-instr/
// quad) but the [0,kCHW-4] clamp DISPLACED the load window at the image
// front/back while the quad still held valid elements -> absmax 0.40.
// Displacement-with-valid-elements happens for at most TWO (row,lane) pairs
// per image (only when sx%4 != 0):
//   front: srcrow 0   = output row rr=-sy    (c=0, valid iff sy<=0),
//          the one lane with c0s = i0+sx in [-3,-1];
//   back:  srcrow 671 = output row rr=671-sy (c=2, valid iff sy>=0),
//          the one lane with c0s in [221,223].
// R13 adds a surgical fixup: the OWNING thread (wave rr&15, that lane)
// re-stores its quad after its main loop via 4 scalar clamped loads --
// same-thread ordering, no race, ~4 extra loads per image. All other
// clamp engagements involve only masked (invalid) elements: interior
// row-crossing reads masked by cm (R2-proven), invalid rows scale=0.
// Everything else identical to R12 (R6/R8-proven fused structure).

constexpr int kC = 3, kH = 224, kW = 224;
constexpr int kCHW  = kC * kH * kW;  // 150528
constexpr int kROWS = kC * kH;       // 672
constexpr int kQPR  = kW / 4;        // 56 quads per row
constexpr int TB    = 1024;          // 16 waves
constexpr int WVB   = TB / 64;       // 16
constexpr int RPW   = kROWS / WVB;   // 42 rows per wave (exact)
constexpr int NB    = 7;             // batch depth (42 = 6*7)

typedef float f32x4 __attribute__((ext_vector_type(4)));

// 16B load requiring only 4B alignment: clang lowers to load <4 x float>
// align 4 -> one global_load_dwordx4 (unaligned access supported on gfx9+).
__device__ __forceinline__ f32x4 ld16_a4(const float* p) {
    f32x4 r;
    __builtin_memcpy(&r, p, sizeof(r));
    return r;
}

__global__ __launch_bounds__(TB) void shift_norm(
    const float* __restrict__ x, const float* __restrict__ sfy,
    const float* __restrict__ sfx, float* __restrict__ out)
{
    const int img = blockIdx.x;
    const float* __restrict__ xb = x + (size_t)img * kCHW;
    float* __restrict__ ob = out + (size_t)img * kCHW;

    // Replicate reference fp32 order: ((f*2-1)*0.1f)*size, trunc toward zero.
    float ty = sfy[img] * 2.0f - 1.0f; ty *= 0.1f; ty *= (float)kH;
    const int sy = (int)truncf(ty);
    float tx = sfx[img] * 2.0f - 1.0f; tx *= 0.1f; tx *= (float)kW;
    const int sx = (int)truncf(tx);

    // Valid input sub-rectangle (rows/cols of x that survive the shift).
    const int rlo = sy > 0 ? sy : 0;
    const int rhi = kH + (sy < 0 ? sy : 0);
    const int clo = sx > 0 ? sx : 0;
    const int chi = kW + (sx < 0 ? sx : 0);

    const int tid  = threadIdx.x;
    const int lane = tid & 63;
    const int wv   = __builtin_amdgcn_readfirstlane(tid >> 6); // wave-uniform

    // Any nonzero shift introduces zero-fill -> 0 is in the value set, which
    // covers every multiplier-masked (invalid) element's 0 contribution.
    const bool hasfill = (sy != 0) | (sx != 0);
    float vmin = hasfill ? 0.0f : INFINITY;
    float vmax = hasfill ? 0.0f : -INFINITY;

    // ---------------- Phase 1: batched row-wise min/max (R8-proven) --------
    if (lane < kQPR) {
        const int i0 = lane * 4;
        float cm1[4];                     // loop-invariant column validity
        #pragma unroll
        for (int k = 0; k < 4; ++k)
            cm1[k] = ((i0 + k) >= clo && (i0 + k) < chi) ? 1.0f : 0.0f;

        for (int t0 = 0; t0 < RPW; t0 += NB) {   // 6 batches of 7
            f32x4 v[NB];
            #pragma unroll
            for (int u = 0; u < NB; ++u) {
                const int rr = wv + (t0 + u) * WVB;   // row in [0, C*H)
                v[u] = *(const f32x4*)(xb + rr * kW + i0);
            }
            #pragma unroll
            for (int u = 0; u < NB; ++u) {
                const int rr = wv + (t0 + u) * WVB;
                const int j  = rr % kH;               // wave-uniform scalar
                const float srm = (j >= rlo && j < rhi) ? 1.0f : 0.0f;
                #pragma unroll
                for (int k = 0; k < 4; ++k) {
                    const float val = v[u][k] * cm1[k] * srm; // invalid -> 0
                    vmin = fminf(vmin, val);
                    vmax = fmaxf(vmax, val);
                }
            }
        }
    }

    // Wave (64-lane) shuffle reduction, then cross-wave via LDS.
    #pragma unroll
    for (int off = 32; off > 0; off >>= 1) {
        vmin = fminf(vmin, __shfl_down(vmin, off));
        vmax = fmaxf(vmax, __shfl_down(vmax, off));
    }
    __shared__ float smin[WVB], smax[WVB];
    __shared__ float s_mn, s_inv;
    if (lane == 0) { smin[tid >> 6] = vmin; smax[tid >> 6] = vmax; }
    __syncthreads();
    if (tid == 0) {
        float mn = smin[0], mx = smax[0];
        #pragma unroll
        for (int w = 1; w < WVB; ++w) {
            mn = fminf(mn, smin[w]);
            mx = fmaxf(mx, smax[w]);
        }
        s_mn  = mn;
        s_inv = 1.0f / (mx - mn);
    }
    __syncthreads();
    const float mn   = s_mn;
    const float inv  = s_inv;
    const float zoff = (0.0f - mn) * inv;

    // ------- Phase 2: single misaligned gather load + fma + aligned store --
    if (lane < kQPR) {
        const int i0   = lane * 4;
        const int c0s  = i0 + sx;         // loop-invariant shifted column base
        float cm[4];
        #pragma unroll
        for (int k = 0; k < 4; ++k)
            cm[k] = ((unsigned)(i0 + k + sx) < (unsigned)kW) ? 1.0f : 0.0f;

        for (int t0 = 0; t0 < RPW; t0 += NB) {   // 6 batches of 7
            f32x4 v[NB];
            #pragma unroll
            for (int u = 0; u < NB; ++u) {
                const int rr = wv + (t0 + u) * WVB;   // output row in [0, C*H)
                const int j  = rr % kH;               // wave-uniform scalar
                const bool rowok = (unsigned)(j + sy) < (unsigned)kH;
                const int srcrow = rowok ? rr + sy : rr;  // clamped (masked)
                int o = srcrow * kW + c0s;            // 4B-aligned flat offset
                o = o < 0 ? 0 : o;                    // clamp into the image
                o = o > kCHW - 4 ? kCHW - 4 : o;      // (fixup handles edges)
                v[u] = ld16_a4(xb + o);               // ONE dwordx4, align 4
            }
            #pragma unroll
            for (int u = 0; u < NB; ++u) {
                const int rr = wv + (t0 + u) * WVB;
                const int j  = rr % kH;
                const float scale =
                    ((unsigned)(j + sy) < (unsigned)kH) ? inv : 0.0f;
                f32x4 o4;
                #pragma unroll
                for (int k = 0; k < 4; ++k)
                    o4[k] = fmaf(v[u][k] * cm[k], scale, zoff); // invalid->zoff
                *(f32x4*)(ob + rr * kW + i0) = o4;    // 16B-aligned store
            }
        }

        // ---- boundary fixup: the <=2 clamp-displaced quads per image ----
        // Front: srcrow 0 is the source of valid output row rr=-sy (c=0)
        // only when sy<=0; the lane with c0s in [-3,-1] had its window
        // clamped 0-o, displacing its valid columns. Re-store correctly.
        if (sy <= 0 && c0s >= -3 && c0s <= -1) {
            const int rr = -sy;                    // j=-sy, jj=0: valid row
            if ((rr & (WVB - 1)) == wv) {          // owning wave & lane
                f32x4 o4;
                #pragma unroll
                for (int k = 0; k < 4; ++k) {
                    const int c = c0s + k;         // source column in row 0
                    o4[k] = ((unsigned)c < (unsigned)kW)
                              ? fmaf(xb[c], inv, zoff) : zoff;
                }
                *(f32x4*)(ob + rr * kW + i0) = o4;
            }
        }
        // Back: srcrow 671 feeds valid output row rr=671-sy (c=2) only when
        // sy>=0; the lane with c0s in [221,223] was clamped kCHW-4.
        if (sy >= 0 && c0s >= 221 && c0s <= 223) {
            const int rr = kROWS - 1 - sy;         // j=223-sy, jj=223: valid
            if ((rr & (WVB - 1)) == wv) {
                const float* __restrict__ srcr = xb + (kROWS - 1) * kW;
                f32x4 o4;
                #pragma unroll
                for (int k = 0; k < 4; ++k) {
                    const int c = c0s + k;         // source column in row 671
                    o4[k] = ((unsigned)c < (unsigned)kW)
                              ? fmaf(srcr[c], inv, zoff) : zoff;
                }
                *(f32x4*)(ob + rr * kW + i0) = o4;
            }
        }
    }
}

extern "C" void kernel_launch(void* const* d_in, const int* in_sizes, int n_in,
                              void* d_out, int out_size, void* d_ws, size_t ws_size,
                              hipStream_t stream) {
    const float* x  = (const float*)d_in[0];
    const float* fy = (const float*)d_in[1];
    const float* fx = (const float*)d_in[2];
    float* out = (float*)d_out;
    const int B = in_sizes[1];  // shift_fy has one element per image
    shift_norm<<<B, TB, 0, stream>>>(x, fy, fx, out);
}